// Round 5
// baseline (444.696 us; speedup 1.0000x reference)
//
#include <hip/hip_runtime.h>

// ---------------------------------------------------------------------------
// AllTnn: locally-connected net, B=128, fp32 (FC via bf16 MFMA).
//  L0: x[128,3,224,224] * w0[55,55,16,3,8,8] (s4) + b0 -> [128,16,55,55]
//      flatten 4x4 -> [128,220,220], relu, LN(220x220)*g0+be0, maxpool2 -> P[128,110,110]
//  L1: P * w1[53,53,9,1,6,6] (s2) + b1 -> [128,9,53,53]
//      flatten 3x3 -> [128,159,159], relu, LN(159x159)*g1+be1
//  FC: [128,25281] @ fcw[1000,25281]^T + fcb -> softmax -> out[128,1000]
// ---------------------------------------------------------------------------

typedef __attribute__((ext_vector_type(8))) short short8;
typedef __attribute__((ext_vector_type(4))) float float4v;

__device__ __forceinline__ short f2bf(float f) {
    unsigned u = __float_as_uint(f);
    u += 0x7FFFu + ((u >> 16) & 1u);        // round-to-nearest-even
    return (short)(u >> 16);
}

// ======================= conv0: locally connected layer 0 ===================
// R9: same LDS-line-staged skeleton as R6 (staging/double-buffer/barrier
// rhythm verbatim), but compute remapped from (b4 x o4 x 2loc, acc 32,
// 2 LDS reads / 16 FMA) to (b4 x o8 x 1loc, acc 32, 1 distinct-addr read +
// 2 broadcast quads / 32 FMA). R6 was LDS-pipe-bound: 12 waves x 16
// distinct b128 reads x ~12cyc > FMA 1536 cyc per line period (VALUBusy 22%).
// Now LDS ~1340 vs FMA 1536 cyc -> VALU-leading, HBM (238 MB ~38 us) is the
// floor. Grid 55 oh x 14 tw = 770 (3 blocks/CU, w0 fetched once),
// tw-major XCD chunks.
__global__ __launch_bounds__(256, 4) void k_conv0(const float* __restrict__ x,
                                                  const float* __restrict__ w0,
                                                  const float* __restrict__ b0,
                                                  float* __restrict__ y0)
{
    __shared__ float xs[2][20 * 132];      // [buf][col][b], P=132 (528B, 16B-mult)
    __shared__ float wsd[2][512];          // [buf][l][kc][o]

    const int t = threadIdx.x;
    // bijective XCD-chunk swizzle over 770 blocks (770 = 8*96+2)
    const int orig = blockIdx.x;
    const int xcd = orig & 7, lin = orig >> 3;
    const int bid = (xcd < 2 ? xcd * 97 : 194 + (xcd - 2) * 96) + lin;
    const int tw = bid / 55;               // 0..13 (tile of 4 ow locs)
    const int oh = bid % 55;
    const bool lastT = (tw == 13);         // locs 52..54 only, 16 valid cols

    // x strip: cols 16*tw .. +19 of rows 4*oh .. +7 (per ch)
    const float* xrow0 = x + (oh << 2) * 224 + (tw << 4);
    const float* wbase = w0 + (oh * 55 + (tw << 2)) * 3072;

    // ---- x staging roles: 640 quads (sb=b 0..127, sc=col-quad 0..4),
    //      col-fastest lane order => coalesced 80B global segments.
    int sb[3], sc[3], gsc[3];
    #pragma unroll
    for (int i = 0; i < 3; ++i) {
        int q = t + (i << 8);
        sb[i] = q / 5;
        sc[i] = q - sb[i] * 5;
        gsc[i] = (lastT && sc[i] > 3) ? 3 : sc[i];   // clamp: stay in row (junk col, unread)
    }
    const int nq = (t < 128) ? 3 : 2;

    // ---- w staging: threads 0..127 -> (l, o, half); 4 scalar LDS writes each
    const int wlm  = t >> 5;               // l 0..3
    const int wom  = (t & 31) >> 1;        // o 0..15
    const int whm  = t & 1;                // kcol half
    const bool wact = (t < 128);
    const int wl_l = ((tw << 2) + wlm > 54) ? 0 : wlm;   // clamp last-tile OOB loc
    const float* wq_base = wbase + wl_l * 3072 + wom * 192 + (whm << 2);

    const int bq = t & 31;                 // b quad base = 4*bq
    const int og = (t >> 5) & 1;           // o oct base = 8*og
    const int lp = t >> 6;                 // loc 0..3 (wave-uniform)

    float4 xv[3];
    float4 wv = make_float4(0.f, 0.f, 0.f, 0.f);
    // prologue: issue line 0 (ch=0, rw=0)
    #pragma unroll
    for (int i = 0; i < 3; ++i)
        if (i < nq) xv[i] = *(const float4*)(xrow0 + sb[i] * 150528 + (gsc[i] << 2));
    if (wact) wv = *(const float4*)(wq_base);

    float acc[4][8] = {};                  // [b4][o j], 32 floats

    #pragma unroll 2
    for (int k = 0; k < 24; ++k) {
        float* xb = xs[k & 1];
        float* wb = wsd[k & 1];
        // store staged regs into buf[k&1] (vmcnt wait inserted by compiler)
        #pragma unroll
        for (int i = 0; i < 3; ++i) {
            if (i < nq) {
                float* d = xb + (sc[i] << 2) * 132 + sb[i];
                d[0] = xv[i].x; d[132] = xv[i].y; d[264] = xv[i].z; d[396] = xv[i].w;
            }
        }
        if (wact) {
            float* d = wb + (wlm << 7) + (whm << 6) + wom;   // [l][kc=4h+u][o]
            d[0] = wv.x; d[16] = wv.y; d[32] = wv.z; d[48] = wv.w;
        }
        // issue next line's global loads (land during compute phase)
        if (k < 23) {
            const int kn = k + 1;
            const int ch = kn >> 3, rw = kn & 7;
            const float* xr = xrow0 + ch * 50176 + rw * 224;
            #pragma unroll
            for (int i = 0; i < 3; ++i)
                if (i < nq) xv[i] = *(const float4*)(xr + sb[i] * 150528 + (gsc[i] << 2));
            if (wact) wv = *(const float4*)(wq_base + (ch << 6) + (rw << 3));
        }
        __syncthreads();                   // single barrier/line
        #pragma unroll
        for (int kc = 0; kc < 8; ++kc) {
            // 1 distinct-addr b128 (32 lanes x 16B = 512B, 2-way dup = free)
            float4 xq  = *(const float4*)(xb + ((lp << 2) + kc) * 132 + (bq << 2));
            // 2 broadcast quads (2 distinct addrs per wave)
            float4 wqA = *(const float4*)(wb + (lp << 7) + (kc << 4) + (og << 3));
            float4 wqB = *(const float4*)(wb + (lp << 7) + (kc << 4) + (og << 3) + 4);
            const float xr4[4] = {xq.x, xq.y, xq.z, xq.w};
            const float wr8[8] = {wqA.x, wqA.y, wqA.z, wqA.w,
                                  wqB.x, wqB.y, wqB.z, wqB.w};
            #pragma unroll
            for (int b4 = 0; b4 < 4; ++b4)
                #pragma unroll
                for (int j = 0; j < 8; ++j)
                    acc[b4][j] += xr4[b4] * wr8[j];
        }
    }

    // epilogue: bias + relu + flattened store
    // o = 8og + j -> row = 4oh + 2og + (j>>2), col = 4ow + (j&3)
    const int ow = (tw << 2) + lp;
    if (ow < 55) {
        const int loc = oh * 55 + ow;
        float bias[8];
        #pragma unroll
        for (int j = 0; j < 8; ++j)
            bias[j] = b0[((og << 3) + j) * 3025 + loc];
        float* ybase = y0 + ((oh << 2) + (og << 1)) * 220 + (ow << 2);
        #pragma unroll
        for (int b4 = 0; b4 < 4; ++b4) {
            const int b = (bq << 2) + b4;
            float ov[8];
            #pragma unroll
            for (int j = 0; j < 8; ++j) {
                float v = acc[b4][j] + bias[j];
                ov[j] = v > 0.f ? v : 0.f;
            }
            float4 o4a, o4b;
            o4a.x = ov[0]; o4a.y = ov[1]; o4a.z = ov[2]; o4a.w = ov[3];
            o4b.x = ov[4]; o4b.y = ov[5]; o4b.z = ov[6]; o4b.w = ov[7];
            *(float4*)(ybase + b * 48400)       = o4a;
            *(float4*)(ybase + b * 48400 + 220) = o4b;
        }
    }
}

// ======================= per-sample mean / rstd =============================
__global__ void k_stats(const float* __restrict__ src, float2* __restrict__ stats, int count)
{
    const int b = blockIdx.x, t = threadIdx.x;
    const float* p = src + (long)b * count;
    const int nq = count >> 2;
    float s = 0.f, s2 = 0.f;
    for (int i = t; i < nq; i += 256) {
        float4 v = *(const float4*)(p + (i << 2));
        s  += (v.x + v.y) + (v.z + v.w);
        s2 += (v.x * v.x + v.y * v.y) + (v.z * v.z + v.w * v.w);
    }
    if (t == 0 && (count & 3)) {
        for (int i = nq << 2; i < count; ++i) { float v = p[i]; s += v; s2 += v * v; }
    }
    #pragma unroll
    for (int off = 32; off > 0; off >>= 1) {
        s  += __shfl_down(s,  off, 64);
        s2 += __shfl_down(s2, off, 64);
    }
    __shared__ float rs[4], rs2[4];
    if ((t & 63) == 0) { rs[t >> 6] = s; rs2[t >> 6] = s2; }
    __syncthreads();
    if (t == 0) {
        float S  = rs[0] + rs[1] + rs[2] + rs[3];
        float S2 = rs2[0] + rs2[1] + rs2[2] + rs2[3];
        float m  = S / count;
        float var = S2 / count - m * m;
        stats[b] = make_float2(m, rsqrtf(var + 1e-5f));
    }
}

// =============== layer0: normalize + affine + 2x2 maxpool ===================
__global__ void k_pool(const float* __restrict__ y0, const float2* __restrict__ st,
                       const float* __restrict__ g0, const float* __restrict__ be0,
                       float* __restrict__ P)
{
    int idx = blockIdx.x * 256 + threadIdx.x;
    if (idx >= 128 * 110 * 110) return;
    int b = idx / 12100, r = idx % 12100;
    int ph = r / 110, pw = r % 110;
    float2 s = st[b];
    int gb = (ph * 220 + pw) * 2;        // 2ph*220 + 2pw
    const float* yb = y0 + b * 48400 + gb;
    float2 a0 = *(const float2*)yb;
    float2 a1 = *(const float2*)(yb + 220);
    float2 ga0 = *(const float2*)(g0 + gb),  ga1 = *(const float2*)(g0 + gb + 220);
    float2 ba0 = *(const float2*)(be0 + gb), ba1 = *(const float2*)(be0 + gb + 220);
    float n0 = (a0.x - s.x) * s.y * ga0.x + ba0.x;
    float n1 = (a0.y - s.x) * s.y * ga0.y + ba0.y;
    float n2 = (a1.x - s.x) * s.y * ga1.x + ba1.x;
    float n3 = (a1.y - s.x) * s.y * ga1.y + ba1.y;
    P[idx] = fmaxf(fmaxf(n0, n1), fmaxf(n2, n3));
}

// ======================= conv1: locally connected layer 1 ===================
// block = 128 thr (lane = b), one (oh,ow) location; 9 o, K=36.
__global__ __launch_bounds__(128) void k_conv1(const float* __restrict__ P,
                                               const float* __restrict__ w1,
                                               const float* __restrict__ b1,
                                               float* __restrict__ y1)
{
    __shared__ float wloc[324];
    __shared__ float pat[128 * 64];      // [b][16 chunks] XOR-swizzled
    const int t = threadIdx.x;
    const int loc = blockIdx.x;
    const int oh = loc / 53, ow = loc % 53;
    for (int e = t; e < 324; e += 128) wloc[e] = w1[loc * 324 + e];
    #pragma unroll
    for (int i = 0; i < 9; ++i) {
        int q = t + (i << 7);            // [0,1152)
        int b_r = q / 9, c = q % 9;
        float pv[4];
        #pragma unroll
        for (int u = 0; u < 4; ++u) {
            int sidx = (c << 2) + u;     // < 36
            int ki = sidx / 6, kj = sidx % 6;
            pv[u] = P[b_r * 12100 + ((oh << 1) + ki) * 110 + (ow << 1) + kj];
        }
        float4 pq; pq.x = pv[0]; pq.y = pv[1]; pq.z = pv[2]; pq.w = pv[3];
        *(float4*)&pat[(b_r << 6) + ((c ^ (b_r & 15)) << 2)] = pq;
    }
    __syncthreads();
    const int b = t;
    float acc[9];
    #pragma unroll
    for (int o = 0; o < 9; ++o) acc[o] = b1[o * 2809 + loc];
    #pragma unroll
    for (int s4 = 0; s4 < 9; ++s4) {
        float4 pq = *(const float4*)&pat[(b << 6) + ((s4 ^ (b & 15)) << 2)];
        #pragma unroll
        for (int o = 0; o < 9; ++o) {
            float4 wq = *(const float4*)&wloc[o * 36 + (s4 << 2)];
            acc[o] += pq.x * wq.x + pq.y * wq.y + pq.z * wq.z + pq.w * wq.w;
        }
    }
    #pragma unroll
    for (int o = 0; o < 9; ++o) {
        float v = acc[o] > 0.f ? acc[o] : 0.f;
        // flatten 3x3: row = 3*oh + o/3, col = 3*ow + o%3
        y1[b * 25281 + (3 * oh + o / 3) * 159 + 3 * ow + o % 3] = v;
    }
}

// ============ layer1 normalize -> hb[b][25600] (bf16, zero-padded) ==========
__global__ void k_normb(const float* __restrict__ y1, const float2* __restrict__ st,
                        const float* __restrict__ g1, const float* __restrict__ be1,
                        unsigned short* __restrict__ hb)
{
    int idx = blockIdx.x * 256 + threadIdx.x;   // < 128*25600
    int b = idx / 25600, k = idx % 25600;
    float v = 0.f;
    if (k < 25281) {
        float2 s = st[b];
        v = (y1[b * 25281 + k] - s.x) * s.y * g1[k] + be1[k];
    }
    hb[idx] = (unsigned short)f2bf(v);
}

// =============== FC: 128x1000 GEMM, bf16 MFMA, LDS-staged B =================
// R8: B (fcw, odd stride 25281) staged per 64x64-k chunk into LDS by all 256
// threads as COALESCED dword streams, cvt to bf16, [64][72] pad; double-
// buffered, register-prefetched, one barrier per chunk. B-frag = one aligned
// ds_read_b128. grid = (16 n-blocks of 64) x (50 k-splits of 512).
__global__ __launch_bounds__(256) void k_fc_mfma(const unsigned short* __restrict__ hb,
                                                 const float* __restrict__ fcw,
                                                 float* __restrict__ pp)
{
    __shared__ unsigned short bs[2][64 * 72];   // [buf][n][k] bf16, pad 72

    const int t    = threadIdx.x;
    const int lane = t & 63;
    const int wave = t >> 6;
    const int n0b  = blockIdx.x << 6;           // block col base (64 cols)
    const int k0   = blockIdx.y << 9;           // 512 K per block
    const int m16  = lane & 15;
    const int q    = lane >> 4;                 // 0..3
    const int nc   = n0b + (wave << 4) + m16;   // this lane's col

    // ---- staging role: 4096 dwords/chunk, 16/thread; f=i*256+t ->
    //      row = i*4 + (t>>6) (wave-uniform), k = t&63 (lane = consecutive)
    const int sk   = t & 63;
    const int rb   = t >> 6;
    int srow[16];                               // clamped fcw rows
    #pragma unroll
    for (int i = 0; i < 16; ++i) {
        int nr = n0b + (i << 2) + rb;
        srow[i] = nr < 1000 ? nr : 999;
    }

    float4v acc[8];
    #pragma unroll
    for (int i = 0; i < 8; ++i) acc[i] = (float4v){0.f, 0.f, 0.f, 0.f};

    const unsigned short* ha = hb + m16 * 25600;   // A row for this lane

    float sv[16];
    // prologue: issue chunk 0 loads (k0 + sk)
    {
        const int gk = k0 + sk;
        const bool ok = gk < 25281;
        #pragma unroll
        for (int i = 0; i < 16; ++i)
            sv[i] = ok ? fcw[(size_t)srow[i] * 25281 + gk] : 0.f;
    }

    #pragma unroll 2
    for (int cc = 0; cc < 8; ++cc) {
        unsigned short* bb = bs[cc & 1];
        // store staged regs (cvt fp32->bf16); wave-uniform row, lane-consec k
        #pragma unroll
        for (int i = 0; i < 16; ++i)
            bb[((i << 2) + rb) * 72 + sk] = (unsigned short)f2bf(sv[i]);
        // issue next chunk's loads (land during compute)
        if (cc < 7) {
            const int gk = k0 + ((cc + 1) << 6) + sk;
            const bool ok = gk < 25281;
            #pragma unroll
            for (int i = 0; i < 16; ++i)
                sv[i] = ok ? fcw[(size_t)srow[i] * 25281 + gk] : 0.f;
        }
        __syncthreads();                   // buf[cc&1] ready (single barrier:
                                           // cc+1 stores hit the other buffer)
        #pragma unroll
        for (int c2 = 0; c2 < 2; ++c2) {
            const int klocal = (c2 << 5) + (q << 3);      // within 64-chunk
            short8 bf = *(const short8*)&bb[((wave << 4) + m16) * 72 + klocal];
            const int kb = k0 + (cc << 6) + klocal;       // global k base
            #pragma unroll
            for (int mt = 0; mt < 8; ++mt) {
                short8 af = *(const short8*)(ha + mt * 16 * 25600 + kb);
                acc[mt] = __builtin_amdgcn_mfma_f32_16x16x32_bf16(af, bf, acc[mt], 0, 0, 0);
            }
        }
    }

    // ---- store partials: D row = q*4+i (within 16-tile), col = nc
    float* prow = pp + ((size_t)blockIdx.y << 17);        // [bz][128][1024]
    #pragma unroll
    for (int mt = 0; mt < 8; ++mt) {
        const int mb = (mt << 4) + (q << 2);
        #pragma unroll
        for (int i = 0; i < 4; ++i)
            prow[(size_t)(mb + i) * 1024 + nc] = acc[mt][i];
    }
}

// ================= reduce K-partials + bias + softmax =======================
__global__ void k_softmax(const float* __restrict__ partials, const float* __restrict__ fcb,
                          float* __restrict__ out)
{
    const int b = blockIdx.x, t = threadIdx.x;
    float v[4];
    float mx = -3.4e38f;
    #pragma unroll
    for (int i = 0; i < 4; ++i) {
        int o = t + (i << 8);
        float s = -3.4e38f;
        if (o < 1000) {
            s = fcb[o];
            for (int bz = 0; bz < 50; ++bz)
                s += partials[(((bz << 7) + b) << 10) + o];
        }
        v[i] = s;
        mx = fmaxf(mx, s);
    }
    __shared__ float red[4], red2[4];
    #pragma unroll
    for (int off = 32; off > 0; off >>= 1) mx = fmaxf(mx, __shfl_down(mx, off, 64));
    if ((t & 63) == 0) red[t >> 6] = mx;
    __syncthreads();
    float M = fmaxf(fmaxf(red[0], red[1]), fmaxf(red[2], red[3]));
    float se = 0.f;
    #pragma unroll
    for (int i = 0; i < 4; ++i) {
        int o = t + (i << 8);
        if (o < 1000) { v[i] = expf(v[i] - M); se += v[i]; }
    }
    #pragma unroll
    for (int off = 32; off > 0; off >>= 1) se += __shfl_down(se, off, 64);
    if ((t & 63) == 0) red2[t >> 6] = se;
    __syncthreads();
    float inv = 1.f / (red2[0] + red2[1] + red2[2] + red2[3]);
    #pragma unroll
    for (int i = 0; i < 4; ++i) {
        int o = t + (i << 8);
        if (o < 1000) out[b * 1000 + o] = v[i] * inv;
    }
}

// ===========================================================================
extern "C" void kernel_launch(void* const* d_in, const int* in_sizes, int n_in,
                              void* d_out, int out_size, void* d_ws, size_t ws_size,
                              hipStream_t stream)
{
    const float* x   = (const float*)d_in[0];
    const float* w0  = (const float*)d_in[1];
    const float* b0  = (const float*)d_in[2];
    const float* g0  = (const float*)d_in[3];
    const float* be0 = (const float*)d_in[4];
    const float* w1  = (const float*)d_in[5];
    const float* b1  = (const float*)d_in[6];
    const float* g1  = (const float*)d_in[7];
    const float* be1 = (const float*)d_in[8];
    const float* fcw = (const float*)d_in[9];
    const float* fcb = (const float*)d_in[10];
    float* out = (float*)d_out;
    float* ws  = (float*)d_ws;

    // workspace layout (floats), max 12,618,880 (~50.5 MB):
    //   y0  [0 .. 6,195,200)                 128*220*220
    //   st0 [6,195,200 .. 6,195,456)         128 float2
    //   P   [6,195,456 .. 7,744,256)         128*110*110
    //   y1  [7,744,256 .. 10,980,224)        128*159*159
    //   st1 [10,980,224 .. 10,980,480)       128 float2
    //   hb  [10,980,480 .. 12,618,880)       128*25600 bf16 (ushort)
    //   pp  [0 .. 6,553,600)                 50*128*1024 -- overlays y0/st0/P
    //       (y0/st0/P are dead before k_fc_mfma runs)
    float*  y0  = ws;
    float2* st0 = (float2*)(ws + 6195200);
    float*  P   = ws + 6195456;
    float*  y1  = ws + 7744256;
    float2* st1 = (float2*)(ws + 10980224);
    unsigned short* hb = (unsigned short*)(ws + 10980480);
    float*  pp  = ws;

    hipLaunchKernelGGL(k_conv0,   dim3(770),     dim3(256), 0, stream, x, w0, b0, y0);
    hipLaunchKernelGGL(k_stats,   dim3(128),     dim3(256), 0, stream, y0, st0, 48400);
    hipLaunchKernelGGL(k_pool,    dim3(6050),    dim3(256), 0, stream, y0, st0, g0, be0, P);
    hipLaunchKernelGGL(k_conv1,   dim3(2809),    dim3(128), 0, stream, P, w1, b1, y1);
    hipLaunchKernelGGL(k_stats,   dim3(128),     dim3(256), 0, stream, y1, st1, 25281);
    hipLaunchKernelGGL(k_normb,   dim3(12800),   dim3(256), 0, stream, y1, st1, g1, be1, hb);
    hipLaunchKernelGGL(k_fc_mfma, dim3(16, 50),  dim3(256), 0, stream, hb, fcw, pp);
    hipLaunchKernelGGL(k_softmax, dim3(128),     dim3(256), 0, stream, pp, fcb, out);
}

// Round 6
// 427.176 us; speedup vs baseline: 1.0410x; 1.0410x over previous
//
#include <hip/hip_runtime.h>

// ---------------------------------------------------------------------------
// AllTnn: locally-connected net, B=128, fp32 (FC via bf16 MFMA).
//  L0: x[128,3,224,224] * w0[55,55,16,3,8,8] (s4) + b0 -> [128,16,55,55]
//      flatten 4x4 -> [128,220,220], relu, LN(220x220)*g0+be0, maxpool2 -> P[128,110,110]
//  L1: P * w1[53,53,9,1,6,6] (s2) + b1 -> [128,9,53,53]
//      flatten 3x3 -> [128,159,159], relu, LN(159x159)*g1+be1
//  FC: [128,25281] @ fcw[1000,25281]^T + fcb -> softmax -> out[128,1000]
// ---------------------------------------------------------------------------

typedef __attribute__((ext_vector_type(8))) short short8;
typedef __attribute__((ext_vector_type(4))) float float4v;

__device__ __forceinline__ short f2bf(float f) {
    unsigned u = __float_as_uint(f);
    u += 0x7FFFu + ((u >> 16) & 1u);        // round-to-nearest-even
    return (short)(u >> 16);
}

// ======================= conv0: locally connected layer 0 ===================
// R6 mapping (measured 96-98 us, beat R9's o8 remap 100-104): LDS-line-staged,
// spill-free. Block = (oh, 4-ow tile), 16 o, 128 b; thread owns (b-quad,
// o-quad, 2 locs) -> acc[2][4][4]=32 floats. Per line (24 = ch*row): stage
// x strip [20 col][128 b] (P=132) + w slice [4 l][8 kc][16 o]; double-
// buffered, ONE barrier/line, next line's loads issued before the barrier.
// Grid 55 oh x 14 tw = 770, tw-major XCD chunks.
__global__ __launch_bounds__(256, 4) void k_conv0(const float* __restrict__ x,
                                                  const float* __restrict__ w0,
                                                  const float* __restrict__ b0,
                                                  float* __restrict__ y0)
{
    __shared__ float xs[2][20 * 132];      // [buf][col][b], P=132 (528B, 16B-mult)
    __shared__ float wsd[2][512];          // [buf][l][kc][o]

    const int t = threadIdx.x;
    // bijective XCD-chunk swizzle over 770 blocks (770 = 8*96+2)
    const int orig = blockIdx.x;
    const int xcd = orig & 7, lin = orig >> 3;
    const int bid = (xcd < 2 ? xcd * 97 : 194 + (xcd - 2) * 96) + lin;
    const int tw = bid / 55;               // 0..13 (tile of 4 ow locs)
    const int oh = bid % 55;
    const bool lastT = (tw == 13);         // locs 52..54 only, 16 valid cols

    // x strip: cols 16*tw .. +19 of rows 4*oh .. +7 (per ch)
    const float* xrow0 = x + (oh << 2) * 224 + (tw << 4);
    const float* wbase = w0 + (oh * 55 + (tw << 2)) * 3072;

    // ---- x staging roles: 640 quads (sb=b 0..127, sc=col-quad 0..4),
    //      col-fastest lane order => coalesced 80B global segments.
    int sb[3], sc[3], gsc[3];
    #pragma unroll
    for (int i = 0; i < 3; ++i) {
        int q = t + (i << 8);
        sb[i] = q / 5;
        sc[i] = q - sb[i] * 5;
        gsc[i] = (lastT && sc[i] > 3) ? 3 : sc[i];   // clamp: stay in row (junk col, unread)
    }
    const int nq = (t < 128) ? 3 : 2;

    // ---- w staging: threads 0..127 -> (l, o, half); 4 scalar LDS writes each
    const int wlm  = t >> 5;               // l 0..3
    const int wom  = (t & 31) >> 1;        // o 0..15
    const int whm  = t & 1;                // kcol half
    const bool wact = (t < 128);
    const int wl_l = ((tw << 2) + wlm > 54) ? 0 : wlm;   // clamp last-tile OOB loc
    const float* wq_base = wbase + wl_l * 3072 + wom * 192 + (whm << 2);

    const int bq = t & 31;                 // b quad base = 4*bq
    const int oq = (t >> 5) & 3;           // o quad base = 4*oq
    const int lp = t >> 7;                 // loc pair: l = 2*lp + i

    float4 xv[3];
    float4 wv = make_float4(0.f, 0.f, 0.f, 0.f);
    // prologue: issue line 0 (ch=0, rw=0)
    #pragma unroll
    for (int i = 0; i < 3; ++i)
        if (i < nq) xv[i] = *(const float4*)(xrow0 + sb[i] * 150528 + (gsc[i] << 2));
    if (wact) wv = *(const float4*)(wq_base);

    float acc[2][4][4] = {};

    #pragma unroll 2
    for (int k = 0; k < 24; ++k) {
        float* xb = xs[k & 1];
        float* wb = wsd[k & 1];
        // store staged regs into buf[k&1] (vmcnt wait inserted by compiler)
        #pragma unroll
        for (int i = 0; i < 3; ++i) {
            if (i < nq) {
                float* d = xb + (sc[i] << 2) * 132 + sb[i];
                d[0] = xv[i].x; d[132] = xv[i].y; d[264] = xv[i].z; d[396] = xv[i].w;
            }
        }
        if (wact) {
            float* d = wb + (wlm << 7) + (whm << 6) + wom;   // [l][kc=4h+u][o]
            d[0] = wv.x; d[16] = wv.y; d[32] = wv.z; d[48] = wv.w;
        }
        // issue next line's global loads (land during compute phase)
        if (k < 23) {
            const int kn = k + 1;
            const int ch = kn >> 3, rw = kn & 7;
            const float* xr = xrow0 + ch * 50176 + rw * 224;
            #pragma unroll
            for (int i = 0; i < 3; ++i)
                if (i < nq) xv[i] = *(const float4*)(xr + sb[i] * 150528 + (gsc[i] << 2));
            if (wact) wv = *(const float4*)(wq_base + (ch << 6) + (rw << 3));
        }
        __syncthreads();                   // single barrier/line
        #pragma unroll
        for (int i = 0; i < 2; ++i) {
            const int l = (lp << 1) + i;   // 0..3, all valid (no guard)
            #pragma unroll
            for (int kc = 0; kc < 8; ++kc) {
                float4 xq = *(const float4*)(xb + ((l << 2) + kc) * 132 + (bq << 2));
                float4 wq = *(const float4*)(wb + (l << 7) + (kc << 4) + (oq << 2));
                const float xr4[4] = {xq.x, xq.y, xq.z, xq.w};
                const float wr4[4] = {wq.x, wq.y, wq.z, wq.w};
                #pragma unroll
                for (int b4 = 0; b4 < 4; ++b4)
                    #pragma unroll
                    for (int j = 0; j < 4; ++j)
                        acc[i][b4][j] += xr4[b4] * wr4[j];
            }
        }
    }

    // epilogue: bias + relu + flattened store (row = 4oh+oq, col = 4ow+j)
    #pragma unroll
    for (int i = 0; i < 2; ++i) {
        const int l = (lp << 1) + i;
        const int ow = (tw << 2) + l;
        if (ow < 55) {
            const int loc = oh * 55 + ow;
            float bias[4];
            #pragma unroll
            for (int j = 0; j < 4; ++j)
                bias[j] = b0[((oq << 2) + j) * 3025 + loc];
            float* ybase = y0 + ((oh << 2) + oq) * 220 + (ow << 2);
            #pragma unroll
            for (int b4 = 0; b4 < 4; ++b4) {
                const int b = (bq << 2) + b4;
                float ov[4];
                #pragma unroll
                for (int j = 0; j < 4; ++j) {
                    float v = acc[i][b4][j] + bias[j];
                    ov[j] = v > 0.f ? v : 0.f;
                }
                float4 o4;
                o4.x = ov[0]; o4.y = ov[1]; o4.z = ov[2]; o4.w = ov[3];
                *(float4*)(ybase + b * 48400) = o4;
            }
        }
    }
}

// ================= per-sample mean/rstd: stage 1 (partials) =================
// R10: old k_stats ran 128 blocks = 0.5 block/CU (half the GPU idle) with a
// 47-iteration sequential load loop -> latency-bound tens of us. Now grid
// (128 b x 8 slices) = 1024 blocks; each block reduces a 1/8 slice with
// coalesced float4 loads -> part[b][8] = (sum, sumsq).
__global__ void k_stats_p(const float* __restrict__ src, float2* __restrict__ part,
                          int count)
{
    const int b = blockIdx.x, s = blockIdx.y, t = threadIdx.x;
    const float* p = src + (long)b * count;
    const int nq = count >> 2;
    float sum = 0.f, sum2 = 0.f;
    for (int i = (s << 8) + t; i < nq; i += 2048) {
        float4 v = *(const float4*)(p + (i << 2));
        sum  += (v.x + v.y) + (v.z + v.w);
        sum2 += (v.x * v.x + v.y * v.y) + (v.z * v.z + v.w * v.w);
    }
    if (s == 0 && t == 0 && (count & 3)) {
        for (int i = nq << 2; i < count; ++i) { float v = p[i]; sum += v; sum2 += v * v; }
    }
    #pragma unroll
    for (int off = 32; off > 0; off >>= 1) {
        sum  += __shfl_down(sum,  off, 64);
        sum2 += __shfl_down(sum2, off, 64);
    }
    __shared__ float rs[4], rs2[4];
    if ((t & 63) == 0) { rs[t >> 6] = sum; rs2[t >> 6] = sum2; }
    __syncthreads();
    if (t == 0)
        part[(b << 3) + s] = make_float2(rs[0] + rs[1] + rs[2] + rs[3],
                                         rs2[0] + rs2[1] + rs2[2] + rs2[3]);
}

// ================= per-sample mean/rstd: stage 2 (finalize) =================
__global__ void k_stats_f(const float2* __restrict__ part, float2* __restrict__ stats,
                          int count)
{
    const int b = threadIdx.x;             // 1 block, 128 threads
    float S = 0.f, S2 = 0.f;
    #pragma unroll
    for (int s = 0; s < 8; ++s) {
        float2 v = part[(b << 3) + s];
        S += v.x; S2 += v.y;
    }
    float m   = S / count;
    float var = S2 / count - m * m;
    stats[b] = make_float2(m, rsqrtf(var + 1e-5f));
}

// =============== layer0: normalize + affine + 2x2 maxpool ===================
__global__ void k_pool(const float* __restrict__ y0, const float2* __restrict__ st,
                       const float* __restrict__ g0, const float* __restrict__ be0,
                       float* __restrict__ P)
{
    int idx = blockIdx.x * 256 + threadIdx.x;
    if (idx >= 128 * 110 * 110) return;
    int b = idx / 12100, r = idx % 12100;
    int ph = r / 110, pw = r % 110;
    float2 s = st[b];
    int gb = (ph * 220 + pw) * 2;        // 2ph*220 + 2pw
    const float* yb = y0 + b * 48400 + gb;
    float2 a0 = *(const float2*)yb;
    float2 a1 = *(const float2*)(yb + 220);
    float2 ga0 = *(const float2*)(g0 + gb),  ga1 = *(const float2*)(g0 + gb + 220);
    float2 ba0 = *(const float2*)(be0 + gb), ba1 = *(const float2*)(be0 + gb + 220);
    float n0 = (a0.x - s.x) * s.y * ga0.x + ba0.x;
    float n1 = (a0.y - s.x) * s.y * ga0.y + ba0.y;
    float n2 = (a1.x - s.x) * s.y * ga1.x + ba1.x;
    float n3 = (a1.y - s.x) * s.y * ga1.y + ba1.y;
    P[idx] = fmaxf(fmaxf(n0, n1), fmaxf(n2, n3));
}

// ======================= conv1: locally connected layer 1 ===================
// block = 128 thr (lane = b), one (oh,ow) location; 9 o, K=36.
__global__ __launch_bounds__(128) void k_conv1(const float* __restrict__ P,
                                               const float* __restrict__ w1,
                                               const float* __restrict__ b1,
                                               float* __restrict__ y1)
{
    __shared__ float wloc[324];
    __shared__ float pat[128 * 64];      // [b][16 chunks] XOR-swizzled
    const int t = threadIdx.x;
    const int loc = blockIdx.x;
    const int oh = loc / 53, ow = loc % 53;
    for (int e = t; e < 324; e += 128) wloc[e] = w1[loc * 324 + e];
    #pragma unroll
    for (int i = 0; i < 9; ++i) {
        int q = t + (i << 7);            // [0,1152)
        int b_r = q / 9, c = q % 9;
        float pv[4];
        #pragma unroll
        for (int u = 0; u < 4; ++u) {
            int sidx = (c << 2) + u;     // < 36
            int ki = sidx / 6, kj = sidx % 6;
            pv[u] = P[b_r * 12100 + ((oh << 1) + ki) * 110 + (ow << 1) + kj];
        }
        float4 pq; pq.x = pv[0]; pq.y = pv[1]; pq.z = pv[2]; pq.w = pv[3];
        *(float4*)&pat[(b_r << 6) + ((c ^ (b_r & 15)) << 2)] = pq;
    }
    __syncthreads();
    const int b = t;
    float acc[9];
    #pragma unroll
    for (int o = 0; o < 9; ++o) acc[o] = b1[o * 2809 + loc];
    #pragma unroll
    for (int s4 = 0; s4 < 9; ++s4) {
        float4 pq = *(const float4*)&pat[(b << 6) + ((s4 ^ (b & 15)) << 2)];
        #pragma unroll
        for (int o = 0; o < 9; ++o) {
            float4 wq = *(const float4*)&wloc[o * 36 + (s4 << 2)];
            acc[o] += pq.x * wq.x + pq.y * wq.y + pq.z * wq.z + pq.w * wq.w;
        }
    }
    #pragma unroll
    for (int o = 0; o < 9; ++o) {
        float v = acc[o] > 0.f ? acc[o] : 0.f;
        // flatten 3x3: row = 3*oh + o/3, col = 3*ow + o%3
        y1[b * 25281 + (3 * oh + o / 3) * 159 + 3 * ow + o % 3] = v;
    }
}

// ============ layer1 normalize -> hb[b][25600] (bf16, zero-padded) ==========
__global__ void k_normb(const float* __restrict__ y1, const float2* __restrict__ st,
                        const float* __restrict__ g1, const float* __restrict__ be1,
                        unsigned short* __restrict__ hb)
{
    int idx = blockIdx.x * 256 + threadIdx.x;   // < 128*25600
    int b = idx / 25600, k = idx % 25600;
    float v = 0.f;
    if (k < 25281) {
        float2 s = st[b];
        v = (y1[b * 25281 + k] - s.x) * s.y * g1[k] + be1[k];
    }
    hb[idx] = (unsigned short)f2bf(v);
}

// =============== FC: 128x1000 GEMM, bf16 MFMA, LDS-staged B =================
// R8: B (fcw, odd stride 25281) staged per 64x64-k chunk into LDS by all 256
// threads as COALESCED dword streams, cvt to bf16, [64][72] pad; double-
// buffered, register-prefetched, one barrier per chunk. B-frag = one aligned
// ds_read_b128. grid = (16 n-blocks of 64) x (50 k-splits of 512).
__global__ __launch_bounds__(256) void k_fc_mfma(const unsigned short* __restrict__ hb,
                                                 const float* __restrict__ fcw,
                                                 float* __restrict__ pp)
{
    __shared__ unsigned short bs[2][64 * 72];   // [buf][n][k] bf16, pad 72

    const int t    = threadIdx.x;
    const int lane = t & 63;
    const int wave = t >> 6;
    const int n0b  = blockIdx.x << 6;           // block col base (64 cols)
    const int k0   = blockIdx.y << 9;           // 512 K per block
    const int m16  = lane & 15;
    const int q    = lane >> 4;                 // 0..3
    const int nc   = n0b + (wave << 4) + m16;   // this lane's col

    // ---- staging role: 4096 dwords/chunk, 16/thread; f=i*256+t ->
    //      row = i*4 + (t>>6) (wave-uniform), k = t&63 (lane = consecutive)
    const int sk   = t & 63;
    const int rb   = t >> 6;
    int srow[16];                               // clamped fcw rows
    #pragma unroll
    for (int i = 0; i < 16; ++i) {
        int nr = n0b + (i << 2) + rb;
        srow[i] = nr < 1000 ? nr : 999;
    }

    float4v acc[8];
    #pragma unroll
    for (int i = 0; i < 8; ++i) acc[i] = (float4v){0.f, 0.f, 0.f, 0.f};

    const unsigned short* ha = hb + m16 * 25600;   // A row for this lane

    float sv[16];
    // prologue: issue chunk 0 loads (k0 + sk)
    {
        const int gk = k0 + sk;
        const bool ok = gk < 25281;
        #pragma unroll
        for (int i = 0; i < 16; ++i)
            sv[i] = ok ? fcw[(size_t)srow[i] * 25281 + gk] : 0.f;
    }

    #pragma unroll 2
    for (int cc = 0; cc < 8; ++cc) {
        unsigned short* bb = bs[cc & 1];
        // store staged regs (cvt fp32->bf16); wave-uniform row, lane-consec k
        #pragma unroll
        for (int i = 0; i < 16; ++i)
            bb[((i << 2) + rb) * 72 + sk] = (unsigned short)f2bf(sv[i]);
        // issue next chunk's loads (land during compute)
        if (cc < 7) {
            const int gk = k0 + ((cc + 1) << 6) + sk;
            const bool ok = gk < 25281;
            #pragma unroll
            for (int i = 0; i < 16; ++i)
                sv[i] = ok ? fcw[(size_t)srow[i] * 25281 + gk] : 0.f;
        }
        __syncthreads();                   // buf[cc&1] ready (single barrier:
                                           // cc+1 stores hit the other buffer)
        #pragma unroll
        for (int c2 = 0; c2 < 2; ++c2) {
            const int klocal = (c2 << 5) + (q << 3);      // within 64-chunk
            short8 bf = *(const short8*)&bb[((wave << 4) + m16) * 72 + klocal];
            const int kb = k0 + (cc << 6) + klocal;       // global k base
            #pragma unroll
            for (int mt = 0; mt < 8; ++mt) {
                short8 af = *(const short8*)(ha + mt * 16 * 25600 + kb);
                acc[mt] = __builtin_amdgcn_mfma_f32_16x16x32_bf16(af, bf, acc[mt], 0, 0, 0);
            }
        }
    }

    // ---- store partials: D row = q*4+i (within 16-tile), col = nc
    float* prow = pp + ((size_t)blockIdx.y << 17);        // [bz][128][1024]
    #pragma unroll
    for (int mt = 0; mt < 8; ++mt) {
        const int mb = (mt << 4) + (q << 2);
        #pragma unroll
        for (int i = 0; i < 4; ++i)
            prow[(size_t)(mb + i) * 1024 + nc] = acc[mt][i];
    }
}

// =============== reduce K-partials + bias (wide, coalesced) =================
// R10: old k_softmax did this with 128 blocks (0.5/CU) x 200 scattered scalar
// loads/thread. Now grid 500 blocks, lane-consecutive o -> coalesced 256B
// per instr, 50 unrolled independent loads/thread. 26 MB ~ 6-8 us.
__global__ void k_red(const float* __restrict__ pp, const float* __restrict__ fcb,
                      float* __restrict__ red)
{
    const int idx = blockIdx.x * 256 + threadIdx.x;    // < 128000
    const int b = idx / 1000, o = idx - b * 1000;
    float s = fcb[o];
    #pragma unroll
    for (int bz = 0; bz < 50; ++bz)
        s += pp[(size_t)(((bz << 7) + b) << 10) + o];
    red[b * 1000 + o] = s;
}

// ===================== softmax on red[128][1000] ============================
__global__ void k_softmax2(const float* __restrict__ red, float* __restrict__ out)
{
    const int b = blockIdx.x, t = threadIdx.x;
    float v[4];
    float mx = -3.4e38f;
    #pragma unroll
    for (int i = 0; i < 4; ++i) {
        int o = t + (i << 8);
        v[i] = (o < 1000) ? red[b * 1000 + o] : -3.4e38f;
        mx = fmaxf(mx, v[i]);
    }
    __shared__ float r1[4], r2[4];
    #pragma unroll
    for (int off = 32; off > 0; off >>= 1) mx = fmaxf(mx, __shfl_down(mx, off, 64));
    if ((t & 63) == 0) r1[t >> 6] = mx;
    __syncthreads();
    float M = fmaxf(fmaxf(r1[0], r1[1]), fmaxf(r1[2], r1[3]));
    float se = 0.f;
    #pragma unroll
    for (int i = 0; i < 4; ++i) {
        int o = t + (i << 8);
        if (o < 1000) { v[i] = expf(v[i] - M); se += v[i]; }
    }
    #pragma unroll
    for (int off = 32; off > 0; off >>= 1) se += __shfl_down(se, off, 64);
    if ((t & 63) == 0) r2[t >> 6] = se;
    __syncthreads();
    float inv = 1.f / (r2[0] + r2[1] + r2[2] + r2[3]);
    #pragma unroll
    for (int i = 0; i < 4; ++i) {
        int o = t + (i << 8);
        if (o < 1000) out[b * 1000 + o] = v[i] * inv;
    }
}

// ===========================================================================
extern "C" void kernel_launch(void* const* d_in, const int* in_sizes, int n_in,
                              void* d_out, int out_size, void* d_ws, size_t ws_size,
                              hipStream_t stream)
{
    const float* x   = (const float*)d_in[0];
    const float* w0  = (const float*)d_in[1];
    const float* b0  = (const float*)d_in[2];
    const float* g0  = (const float*)d_in[3];
    const float* be0 = (const float*)d_in[4];
    const float* w1  = (const float*)d_in[5];
    const float* b1  = (const float*)d_in[6];
    const float* g1  = (const float*)d_in[7];
    const float* be1 = (const float*)d_in[8];
    const float* fcw = (const float*)d_in[9];
    const float* fcb = (const float*)d_in[10];
    float* out = (float*)d_out;
    float* ws  = (float*)d_ws;

    // workspace layout (floats), max 12,618,880 (~50.5 MB):
    //   y0   [0 .. 6,195,200)                128*220*220
    //   st0  [6,195,200 .. 6,195,456)        128 float2
    //   P    [6,195,456 .. 7,744,256)        128*110*110
    //   y1   [7,744,256 .. 10,980,224)       128*159*159
    //   st1  [10,980,224 .. 10,980,480)      128 float2
    //   hb   [10,980,480 .. 12,618,880)      128*25600 bf16 (ushort)
    //   part [7,000,000 .. 7,004,096)        128x8 float2 -- inside P region;
    //        used (a) before P is written, (b) after P is dead. no conflict.
    //   pp   [0 .. 6,553,600)                50*128*1024 -- overlays y0/st0/P
    //   red  [6,553,600 .. 6,681,600)        128*1000 -- after pp, in dead P
    float*  y0  = ws;
    float2* st0 = (float2*)(ws + 6195200);
    float*  P   = ws + 6195456;
    float*  y1  = ws + 7744256;
    float2* st1 = (float2*)(ws + 10980224);
    unsigned short* hb = (unsigned short*)(ws + 10980480);
    float2* part = (float2*)(ws + 7000000);
    float*  pp  = ws;
    float*  red = ws + 6553600;

    hipLaunchKernelGGL(k_conv0,    dim3(770),      dim3(256), 0, stream, x, w0, b0, y0);
    hipLaunchKernelGGL(k_stats_p,  dim3(128, 8),   dim3(256), 0, stream, y0, part, 48400);
    hipLaunchKernelGGL(k_stats_f,  dim3(1),        dim3(128), 0, stream, part, st0, 48400);
    hipLaunchKernelGGL(k_pool,     dim3(6050),     dim3(256), 0, stream, y0, st0, g0, be0, P);
    hipLaunchKernelGGL(k_conv1,    dim3(2809),     dim3(128), 0, stream, P, w1, b1, y1);
    hipLaunchKernelGGL(k_stats_p,  dim3(128, 8),   dim3(256), 0, stream, y1, part, 25281);
    hipLaunchKernelGGL(k_stats_f,  dim3(1),        dim3(128), 0, stream, part, st1, 25281);
    hipLaunchKernelGGL(k_normb,    dim3(12800),    dim3(256), 0, stream, y1, st1, g1, be1, hb);
    hipLaunchKernelGGL(k_fc_mfma,  dim3(16, 50),   dim3(256), 0, stream, hb, fcw, pp);
    hipLaunchKernelGGL(k_red,      dim3(500),      dim3(256), 0, stream, pp, fcb, red);
    hipLaunchKernelGGL(k_softmax2, dim3(128),      dim3(256), 0, stream, red, out);
}